// Round 8
// baseline (397.946 us; speedup 1.0000x reference)
//
#include <hip/hip_runtime.h>

// ---------------------------------------------------------------------------
// SingleHeadAttention: out = softmax(mask((q Wq^T)(k Wk^T)^T / 16)) (v Wv^T)
// B=4, S=4096, D=256, fp32 in/out, bf16 MFMA compute.
// Pass 1: projection GEMM -> ws (Q scaled by log2e/16; V transposed)
// Pass 2: causal flash attention, swapped QK^T (mfma32(K,Q)):
//         256-thr blocks (4 waves = 2 q-subchunks x 2 d-halves) sharing one
//         K tile [32][256] LDS dbuf (global_load_lds, swz16 source).
//         Per wave: 32 q-rows x 128 dims, Q in 64 regs, V reg-prefetch,
//         in-register softmax + P repack.  64-row antithetic chunk pairs
//         + 8-way kv-split; XCD-aware batch map.
// Pass 3: combine the split kv-partials (m/l rescale) -> d_out.
// ---------------------------------------------------------------------------

typedef __bf16 bf16_t;
typedef bf16_t bf16x8 __attribute__((ext_vector_type(8)));
typedef bf16_t bf16x4 __attribute__((ext_vector_type(4)));
typedef float  f32x4  __attribute__((ext_vector_type(4)));
typedef float  f32x16 __attribute__((ext_vector_type(16)));
typedef unsigned int u32;
typedef u32 u32x4 __attribute__((ext_vector_type(4)));

#define MFMA16(a, b, c) __builtin_amdgcn_mfma_f32_16x16x32_bf16((a), (b), (c), 0, 0, 0)
#define MFMA32(a, b, c) __builtin_amdgcn_mfma_f32_32x32x16_bf16((a), (b), (c), 0, 0, 0)

#define GLOAD_LDS16(gsrc, ldst) \
    __builtin_amdgcn_global_load_lds( \
        (const __attribute__((address_space(1))) void*)(gsrc), \
        (__attribute__((address_space(3))) void*)(ldst), 16, 0, 0)

#define NB      4
#define SEQ     4096
#define DM      256
#define NROWS   (NB * SEQ)            // 16384
#define NELEM   ((size_t)NROWS * DM)  // 4194304
#define QSCALE  0.09016844005556021f  // (1/16) * log2(e)
#define DEFER_THR 8.0f                // defer-max threshold (log2 domain)

// XOR swizzle for 512B-row tiles (16B granularity) -- proj kernel
__device__ __forceinline__ int swz(int row, int bytecol) {
    return bytecol ^ ((row & 7) << 4);
}

__device__ __forceinline__ u32 packbf(float a, float b) {
    union { bf16_t h; unsigned short s; } ca, cb;
    ca.h = (bf16_t)a; cb.h = (bf16_t)b;
    return (u32)ca.s | ((u32)cb.s << 16);
}

__device__ __forceinline__ bf16x8 u4_to_b8(u32x4 u) {
    union { u32x4 u; bf16x8 b; } cv; cv.u = u; return cv.b;
}

// ---------------------------------------------------------------------------
// Pass 1: projection GEMM.  out[m][n] = sum_k in[m][k] * W[n][k]
// ---------------------------------------------------------------------------
__global__ __launch_bounds__(256) void proj_kernel(
    const float* __restrict__ qin, const float* __restrict__ kin,
    const float* __restrict__ vin,
    const float* __restrict__ Wq, const float* __restrict__ Wk,
    const float* __restrict__ Wv,
    bf16_t* __restrict__ Qb, bf16_t* __restrict__ Kb, bf16_t* __restrict__ Vt)
{
    __shared__ char a_lds[128 * 64 * 2];
    __shared__ char w_lds[128 * 64 * 2];

    const int z = blockIdx.z;
    const float* in = (z == 0) ? qin : (z == 1) ? kin : vin;
    const float* W  = (z == 0) ? Wq  : (z == 1) ? Wk  : Wv;

    const int m0 = blockIdx.x * 128;
    const int n0 = blockIdx.y * 128;
    const int tid = threadIdx.x;
    const int l  = tid & 63;
    const int w  = tid >> 6;
    const int wr = w >> 1, wc = w & 1;
    const int lg = l >> 4, cl = l & 15;

    f32x4 acc[4][4] = {};

    for (int k0 = 0; k0 < DM; k0 += 64) {
#pragma unroll
        for (int i = 0; i < 8; ++i) {
            int chunk = tid + i * 256;
            int row = chunk >> 4;
            int kk  = (chunk & 15) * 4;
            float4 av = *(const float4*)(in + (size_t)(m0 + row) * DM + k0 + kk);
            bf16x4 ap;
            ap[0] = (bf16_t)av.x; ap[1] = (bf16_t)av.y;
            ap[2] = (bf16_t)av.z; ap[3] = (bf16_t)av.w;
            *(bf16x4*)(a_lds + row * 128 + swz(row, kk * 2)) = ap;

            float4 wv4 = *(const float4*)(W + (size_t)(n0 + row) * DM + k0 + kk);
            bf16x4 wp;
            wp[0] = (bf16_t)wv4.x; wp[1] = (bf16_t)wv4.y;
            wp[2] = (bf16_t)wv4.z; wp[3] = (bf16_t)wv4.w;
            *(bf16x4*)(w_lds + row * 128 + swz(row, kk * 2)) = wp;
        }
        __syncthreads();

#pragma unroll
        for (int ks = 0; ks < 2; ++ks) {
            bf16x8 af[4], bfr[4];
#pragma unroll
            for (int mi = 0; mi < 4; ++mi) {
                int row = wr * 64 + mi * 16 + cl;
                int kb2 = (ks * 32 + lg * 8) * 2;
                af[mi] = *(bf16x8*)(a_lds + row * 128 + swz(row, kb2));
            }
#pragma unroll
            for (int ni = 0; ni < 4; ++ni) {
                int row = wc * 64 + ni * 16 + cl;
                int kb2 = (ks * 32 + lg * 8) * 2;
                bfr[ni] = *(bf16x8*)(w_lds + row * 128 + swz(row, kb2));
            }
#pragma unroll
            for (int mi = 0; mi < 4; ++mi)
#pragma unroll
                for (int ni = 0; ni < 4; ++ni)
                    acc[mi][ni] = MFMA16(af[mi], bfr[ni], acc[mi][ni]);
        }
        __syncthreads();
    }

#pragma unroll
    for (int mi = 0; mi < 4; ++mi) {
#pragma unroll
        for (int ni = 0; ni < 4; ++ni) {
            int mbase = m0 + wr * 64 + mi * 16 + lg * 4;
            int ncol  = n0 + wc * 64 + ni * 16 + cl;
            if (z == 0) {
#pragma unroll
                for (int i = 0; i < 4; ++i)
                    Qb[(size_t)(mbase + i) * DM + ncol] = (bf16_t)(acc[mi][ni][i] * QSCALE);
            } else if (z == 1) {
#pragma unroll
                for (int i = 0; i < 4; ++i)
                    Kb[(size_t)(mbase + i) * DM + ncol] = (bf16_t)acc[mi][ni][i];
            } else {
                int bb = mbase >> 12;
                int s0 = mbase & 4095;
                bf16x4 pk;
                pk[0] = (bf16_t)acc[mi][ni][0]; pk[1] = (bf16_t)acc[mi][ni][1];
                pk[2] = (bf16_t)acc[mi][ni][2]; pk[3] = (bf16_t)acc[mi][ni][3];
                *(bf16x4*)(Vt + ((size_t)bb << 20) + (size_t)ncol * SEQ + s0) = pk;
            }
        }
    }
}

// ---------------------------------------------------------------------------
// Pass 2: causal flash attention, 4-wave blocks, 64-row chunks.
// grid = 128*split.  g -> xcd=g&7, b=xcd>>1, idx=(g>>3)*2+(xcd&1),
// p=idx&31 (antithetic pair of 64-row chunks), sblk=idx>>5.
// Chunk c: q rows [c*64, c*64+64), nt=2c+2 KVB=32 tiles, block slice
// [nt*sblk/split, nt*(sblk+1)/split).  Wave w: qsub=w>>1, dhalf=w&1;
// wave extent ntw=2c+1+qsub (skips tiles past it; mask at t==ntw-1).
// Layouts (mfma_f32_32x32x16_bf16):
//   A: lane l -> row=l&31, k=(l>>5)*8+j ;  B: col=l&31, k=(l>>5)*8+j
//   C: col=l&31, row=(r&3)+8*(r>>2)+4*(l>>5)
// ---------------------------------------------------------------------------
__global__ __launch_bounds__(256, 4) void attn_kernel(
    const bf16_t* __restrict__ Qb, const bf16_t* __restrict__ Kb,
    const bf16_t* __restrict__ Vt,
    float* __restrict__ O0, bf16_t* __restrict__ O1, float* __restrict__ ML,
    int split)
{
    __shared__ __attribute__((aligned(16))) char smem[2 * 16384];  // K dbuf

    const int g = blockIdx.x;
    const int xcd = g & 7;
    const int b = xcd >> 1;
    const int idx = ((g >> 3) << 1) | (xcd & 1);   // [0, 32*split)
    const int p = idx & 31;
    const int sblk = idx >> 5;                     // [0, split)

    const int tid = threadIdx.x;
    const int w = tid >> 6;
    const int qsub  = w >> 1;                      // q-subchunk (32 rows)
    const int dhalf = w & 1;                       // d-half (128 dims)
    const int l = tid & 63;
    const int q5 = l & 31;
    const int hi = l >> 5;
    const int dbase = dhalf * 128;

    char* cur = smem;
    char* nxt = smem + 16384;

    const int segc[2] = { p, 31 - p + 32 };        // {p, 63-p}

    auto stageK = [&](int t, char* dst) {
        const size_t rbase = (size_t)(b * SEQ) + (size_t)t * 32;
#pragma unroll
        for (int i = 0; i < 4; ++i) {
            int chunk = i * 256 + tid;        // [0,1024) 16B chunks
            int row = chunk >> 5;             // [0,32)
            int bc  = (chunk & 31) << 4;      // [0,512) step 16
            int scol = bc ^ ((row & 15) << 4);
            GLOAD_LDS16(Kb + (rbase + row) * DM + (scol >> 1), dst + chunk * 16);
        }
    };

    for (int sg = 0; sg < 2; ++sg) {
        const int c = segc[sg];
        const int nt = 2 * c + 2;                  // block kv tiles
        const int T0 = (nt * sblk) / split;
        const int T1 = (nt * (sblk + 1)) / split;
        const int ntw = 2 * c + 1 + qsub;          // wave causal extent
        const int qbase = c * 64 + qsub * 32;
        const int qg = qbase + q5;

        __syncthreads();   // prior segment's LDS reads complete (all waves)

        // ---- Q fragments: 64 regs (this lane's q row, both k-halves) ----
        const bf16_t* qrow = Qb + (size_t)(b * SEQ + qg) * DM + hi * 8;
        bf16x8 qf[16];
#pragma unroll
        for (int ks = 0; ks < 16; ++ks)
            qf[ks] = *(const bf16x8*)(qrow + ks * 16);

        f32x16 o[4] = {};
        float m_ = -1e30f, ssum = 0.0f;

        if (T0 < T1) stageK(T0, cur);

        for (int t = T0; t < T1; ++t) {
            const int kv0 = t * 32;
            __syncthreads();   // implicit vmcnt(0): K(t) resident in cur

            if (t + 1 < T1) stageK(t + 1, nxt);

            if (t < ntw) {     // wave-uniform causal guard
                // ---- V prefetch: this wave's 128-d half, 8 x 16B ----
                const bf16_t* vbase = Vt + ((size_t)b << 20) + kv0 + hi * 8;
                bf16x8 vreg[8];
#pragma unroll
                for (int db = 0; db < 4; ++db) {
                    const bf16_t* vr = vbase + (size_t)(dbase + db * 32 + q5) * SEQ;
                    vreg[2 * db]     = *(const bf16x8*)(vr);
                    vreg[2 * db + 1] = *(const bf16x8*)(vr + 16);
                }

                // ---- S^T = K Q^T : S[kv][q], two acc chains, K from LDS ----
                f32x16 sA = {}, sB = {};
#pragma unroll
                for (int ks = 0; ks < 16; ++ks) {
                    bf16x8 kf = *(bf16x8*)(cur + q5 * 512 +
                                           ((ks * 32 + hi * 16) ^ ((q5 & 15) << 4)));
                    if (ks & 1) sB = MFMA32(kf, qf[ks], sB);
                    else        sA = MFMA32(kf, qf[ks], sA);
                }
                f32x16 sv = sA + sB;

                // ---- causal mask (wave's diagonal tile only) ----
                if (t == ntw - 1) {
#pragma unroll
                    for (int r = 0; r < 16; ++r) {
                        int kv = kv0 + (r & 3) + 8 * (r >> 2) + 4 * hi;
                        if (kv > qg) sv[r] = -1e30f;
                    }
                }

                // ---- online softmax, lane-local + one shfl ----
                float rm = sv[0];
#pragma unroll
                for (int r = 1; r < 16; ++r) rm = fmaxf(rm, sv[r]);
                rm = fmaxf(rm, __shfl_xor(rm, 32));
                float mn = (rm > m_ + DEFER_THR) ? rm : m_;
                float al = exp2f(m_ - mn);
                m_ = mn;
                float rs = 0.0f;
#pragma unroll
                for (int r = 0; r < 16; ++r) { sv[r] = exp2f(sv[r] - mn); rs += sv[r]; }
                rs += __shfl_xor(rs, 32);
                ssum = ssum * al + rs;
                if (al != 1.0f) {
#pragma unroll
                    for (int db = 0; db < 4; ++db) o[db] *= al;
                }

                // ---- P^T -> bf16 B-fragments (pack + shfl32 + select) ----
                u32 cpk[8], spk[8];
#pragma unroll
                for (int j = 0; j < 8; ++j) cpk[j] = packbf(sv[2 * j], sv[2 * j + 1]);
#pragma unroll
                for (int j = 0; j < 8; ++j) spk[j] = (u32)__shfl_xor((int)cpk[j], 32);
                u32x4 f0, f1;
                f0[0] = hi ? spk[2] : cpk[0];
                f0[1] = hi ? spk[3] : cpk[1];
                f0[2] = hi ? cpk[2] : spk[0];
                f0[3] = hi ? cpk[3] : spk[1];
                f1[0] = hi ? spk[6] : cpk[4];
                f1[1] = hi ? spk[7] : cpk[5];
                f1[2] = hi ? cpk[6] : spk[4];
                f1[3] = hi ? cpk[7] : spk[5];
                bf16x8 pb0 = u4_to_b8(f0);
                bf16x8 pb1 = u4_to_b8(f1);

                // ---- O^T += Vt P^T  (this wave's 128-d half) ----
#pragma unroll
                for (int db = 0; db < 4; ++db) {
                    o[db] = MFMA32(vreg[2 * db],     pb0, o[db]);
                    o[db] = MFMA32(vreg[2 * db + 1], pb1, o[db]);
                }
            }

            char* tmp = cur; cur = nxt; nxt = tmp;
        }

        // ---- write global partial (this wave's 32 q-rows x 128 d) + (m,l) ----
        const size_t row = (size_t)(b * SEQ + qg);
        if (sblk == 0) {
#pragma unroll
            for (int db = 0; db < 4; ++db)
#pragma unroll
                for (int rr = 0; rr < 4; ++rr) {
                    int d = dbase + db * 32 + rr * 8 + hi * 4;
                    f32x4 v4 = { o[db][rr * 4 + 0], o[db][rr * 4 + 1],
                                 o[db][rr * 4 + 2], o[db][rr * 4 + 3] };
                    *(f32x4*)(O0 + row * DM + d) = v4;
                }
        } else {
            bf16_t* O1s = O1 + (size_t)(sblk - 1) * NELEM;
#pragma unroll
            for (int db = 0; db < 4; ++db)
#pragma unroll
                for (int rr = 0; rr < 4; ++rr) {
                    int d = dbase + db * 32 + rr * 8 + hi * 4;
                    bf16x4 v4;
                    v4[0] = (bf16_t)o[db][rr * 4 + 0];
                    v4[1] = (bf16_t)o[db][rr * 4 + 1];
                    v4[2] = (bf16_t)o[db][rr * 4 + 2];
                    v4[3] = (bf16_t)o[db][rr * 4 + 3];
                    *(bf16x4*)(O1s + row * DM + d) = v4;
                }
        }
        if (dhalf == 0 && hi == 0) {
            ML[(row * split + sblk) * 2 + 0] = m_;
            ML[(row * split + sblk) * 2 + 1] = ssum;
        }
    }
}

// ---------------------------------------------------------------------------
// Pass 3: combine split partials.  out = sum_s w_s O_s / sum_s w_s l_s
// ---------------------------------------------------------------------------
__global__ __launch_bounds__(256) void combine_kernel(
    const float* __restrict__ O0, const bf16_t* __restrict__ O1,
    const float* __restrict__ ML, float* __restrict__ out, int split)
{
    const int row = blockIdx.x * 4 + (threadIdx.x >> 6);
    const int l = threadIdx.x & 63;
    const float* mlr = ML + (size_t)row * split * 2;

    float M = -1e30f;
    for (int s = 0; s < split; ++s) M = fmaxf(M, mlr[s * 2]);
    float denom = 0.0f;
    for (int s = 0; s < split; ++s) denom += exp2f(mlr[s * 2] - M) * mlr[s * 2 + 1];
    const float inv = 1.0f / denom;

    const float w0 = exp2f(mlr[0] - M);
    f32x4 a = *(const f32x4*)(O0 + (size_t)row * DM + l * 4);
    f32x4 acc;
#pragma unroll
    for (int j = 0; j < 4; ++j) acc[j] = w0 * a[j];
    for (int s = 1; s < split; ++s) {
        float wss = exp2f(mlr[s * 2] - M);
        bf16x4 bv = *(const bf16x4*)(O1 + (size_t)(s - 1) * NELEM +
                                     (size_t)row * DM + l * 4);
#pragma unroll
        for (int j = 0; j < 4; ++j) acc[j] += wss * (float)bv[j];
    }
    f32x4 r;
#pragma unroll
    for (int j = 0; j < 4; ++j) r[j] = acc[j] * inv;
    *(f32x4*)(out + (size_t)row * DM + l * 4) = r;
}

// ---------------------------------------------------------------------------
extern "C" void kernel_launch(void* const* d_in, const int* in_sizes, int n_in,
                              void* d_out, int out_size, void* d_ws, size_t ws_size,
                              hipStream_t stream) {
    const float* k_in = (const float*)d_in[0];
    const float* q_in = (const float*)d_in[1];
    const float* v_in = (const float*)d_in[2];
    const float* Wk   = (const float*)d_in[3];
    const float* Wq   = (const float*)d_in[4];
    const float* Wv   = (const float*)d_in[5];
    // d_in[6] = causal mask (tril) -- implemented analytically.

    // ws: Qb,Kb,Vt (3*NELEM bf16) + (split-1)*NELEM bf16 partials + ML
    const size_t need8 = NELEM * 2 * 10 + (size_t)NROWS * 8 * 2 * sizeof(float);
    const int split = (ws_size >= need8) ? 8 : 4;

    bf16_t* Qb = (bf16_t*)d_ws;
    bf16_t* Kb = Qb + NELEM;
    bf16_t* Vt = Kb + NELEM;
    bf16_t* O1 = Vt + NELEM;                       // (split-1) bf16 partials
    float*  ML = (float*)(O1 + (size_t)(split - 1) * NELEM);
    float* outp = (float*)d_out;                   // doubles as slot-0 partial

    proj_kernel<<<dim3(NROWS / 128, DM / 128, 3), 256, 0, stream>>>(
        q_in, k_in, v_in, Wq, Wk, Wv, Qb, Kb, Vt);
    attn_kernel<<<128 * split, 256, 0, stream>>>(Qb, Kb, Vt, outp, O1, ML, split);
    combine_kernel<<<NROWS / 4, 256, 0, stream>>>(outp, O1, ML, outp, split);
}

// Round 10
// 177.248 us; speedup vs baseline: 2.2451x; 2.2451x over previous
//
#include <hip/hip_runtime.h>

// ---------------------------------------------------------------------------
// SingleHeadAttention: out = softmax(mask((q Wq^T)(k Wk^T)^T / 16)) (v Wv^T)
// B=4, S=4096, D=256, fp32 in/out, bf16 MFMA compute.
// Pass 1: projection GEMM -> ws (Q scaled by log2e/16; V transposed)
// Pass 2: causal flash attention (round-7 structure, verified):
//         128-thr blocks (2 waves), both waves own the SAME 32 q-rows and
//         SAME kv slice; wave = 128-d half.  K tile [32][256] LDS dbuf via
//         global_load_lds; Q in 64 regs; V issued FIRST (oldest VMEM) so the
//         compiler's counted vmcnt before PV leaves the K-stage in flight.
//         In-register softmax + P repack.  setprio around MFMA clusters.
//         Antithetic chunk pair + 5-way kv-split (5 blocks/CU exact LDS fit).
// Pass 3: combine the 5 kv-partials (m/l rescale) -> d_out.
// ---------------------------------------------------------------------------

typedef __bf16 bf16_t;
typedef bf16_t bf16x8 __attribute__((ext_vector_type(8)));
typedef bf16_t bf16x4 __attribute__((ext_vector_type(4)));
typedef float  f32x4  __attribute__((ext_vector_type(4)));
typedef float  f32x16 __attribute__((ext_vector_type(16)));
typedef unsigned int u32;
typedef u32 u32x4 __attribute__((ext_vector_type(4)));

#define MFMA16(a, b, c) __builtin_amdgcn_mfma_f32_16x16x32_bf16((a), (b), (c), 0, 0, 0)
#define MFMA32(a, b, c) __builtin_amdgcn_mfma_f32_32x32x16_bf16((a), (b), (c), 0, 0, 0)

#define GLOAD_LDS16(gsrc, ldst) \
    __builtin_amdgcn_global_load_lds( \
        (const __attribute__((address_space(1))) void*)(gsrc), \
        (__attribute__((address_space(3))) void*)(ldst), 16, 0, 0)

#define NB      4
#define SEQ     4096
#define DM      256
#define NROWS   (NB * SEQ)            // 16384
#define NELEM   ((size_t)NROWS * DM)  // 4194304
#define QSCALE  0.09016844005556021f  // (1/16) * log2(e)
#define DEFER_THR 8.0f                // defer-max threshold (log2 domain)
#define SPLITG  5                     // kv-split (5 blocks/CU: 5*32KB = 160KB)

// XOR swizzle for 512B-row tiles (16B granularity) -- proj kernel
__device__ __forceinline__ int swz(int row, int bytecol) {
    return bytecol ^ ((row & 7) << 4);
}

__device__ __forceinline__ u32 packbf(float a, float b) {
    union { bf16_t h; unsigned short s; } ca, cb;
    ca.h = (bf16_t)a; cb.h = (bf16_t)b;
    return (u32)ca.s | ((u32)cb.s << 16);
}

__device__ __forceinline__ bf16x8 u4_to_b8(u32x4 u) {
    union { u32x4 u; bf16x8 b; } cv; cv.u = u; return cv.b;
}

// ---------------------------------------------------------------------------
// Pass 1: projection GEMM.  out[m][n] = sum_k in[m][k] * W[n][k]
// ---------------------------------------------------------------------------
__global__ __launch_bounds__(256) void proj_kernel(
    const float* __restrict__ qin, const float* __restrict__ kin,
    const float* __restrict__ vin,
    const float* __restrict__ Wq, const float* __restrict__ Wk,
    const float* __restrict__ Wv,
    bf16_t* __restrict__ Qb, bf16_t* __restrict__ Kb, bf16_t* __restrict__ Vt)
{
    __shared__ char a_lds[128 * 64 * 2];
    __shared__ char w_lds[128 * 64 * 2];

    const int z = blockIdx.z;
    const float* in = (z == 0) ? qin : (z == 1) ? kin : vin;
    const float* W  = (z == 0) ? Wq  : (z == 1) ? Wk  : Wv;

    const int m0 = blockIdx.x * 128;
    const int n0 = blockIdx.y * 128;
    const int tid = threadIdx.x;
    const int l  = tid & 63;
    const int w  = tid >> 6;
    const int wr = w >> 1, wc = w & 1;
    const int lg = l >> 4, cl = l & 15;

    f32x4 acc[4][4] = {};

    for (int k0 = 0; k0 < DM; k0 += 64) {
#pragma unroll
        for (int i = 0; i < 8; ++i) {
            int chunk = tid + i * 256;
            int row = chunk >> 4;
            int kk  = (chunk & 15) * 4;
            float4 av = *(const float4*)(in + (size_t)(m0 + row) * DM + k0 + kk);
            bf16x4 ap;
            ap[0] = (bf16_t)av.x; ap[1] = (bf16_t)av.y;
            ap[2] = (bf16_t)av.z; ap[3] = (bf16_t)av.w;
            *(bf16x4*)(a_lds + row * 128 + swz(row, kk * 2)) = ap;

            float4 wv4 = *(const float4*)(W + (size_t)(n0 + row) * DM + k0 + kk);
            bf16x4 wp;
            wp[0] = (bf16_t)wv4.x; wp[1] = (bf16_t)wv4.y;
            wp[2] = (bf16_t)wv4.z; wp[3] = (bf16_t)wv4.w;
            *(bf16x4*)(w_lds + row * 128 + swz(row, kk * 2)) = wp;
        }
        __syncthreads();

#pragma unroll
        for (int ks = 0; ks < 2; ++ks) {
            bf16x8 af[4], bfr[4];
#pragma unroll
            for (int mi = 0; mi < 4; ++mi) {
                int row = wr * 64 + mi * 16 + cl;
                int kb2 = (ks * 32 + lg * 8) * 2;
                af[mi] = *(bf16x8*)(a_lds + row * 128 + swz(row, kb2));
            }
#pragma unroll
            for (int ni = 0; ni < 4; ++ni) {
                int row = wc * 64 + ni * 16 + cl;
                int kb2 = (ks * 32 + lg * 8) * 2;
                bfr[ni] = *(bf16x8*)(w_lds + row * 128 + swz(row, kb2));
            }
#pragma unroll
            for (int mi = 0; mi < 4; ++mi)
#pragma unroll
                for (int ni = 0; ni < 4; ++ni)
                    acc[mi][ni] = MFMA16(af[mi], bfr[ni], acc[mi][ni]);
        }
        __syncthreads();
    }

#pragma unroll
    for (int mi = 0; mi < 4; ++mi) {
#pragma unroll
        for (int ni = 0; ni < 4; ++ni) {
            int mbase = m0 + wr * 64 + mi * 16 + lg * 4;
            int ncol  = n0 + wc * 64 + ni * 16 + cl;
            if (z == 0) {
#pragma unroll
                for (int i = 0; i < 4; ++i)
                    Qb[(size_t)(mbase + i) * DM + ncol] = (bf16_t)(acc[mi][ni][i] * QSCALE);
            } else if (z == 1) {
#pragma unroll
                for (int i = 0; i < 4; ++i)
                    Kb[(size_t)(mbase + i) * DM + ncol] = (bf16_t)acc[mi][ni][i];
            } else {
                int bb = mbase >> 12;
                int s0 = mbase & 4095;
                bf16x4 pk;
                pk[0] = (bf16_t)acc[mi][ni][0]; pk[1] = (bf16_t)acc[mi][ni][1];
                pk[2] = (bf16_t)acc[mi][ni][2]; pk[3] = (bf16_t)acc[mi][ni][3];
                *(bf16x4*)(Vt + ((size_t)bb << 20) + (size_t)ncol * SEQ + s0) = pk;
            }
        }
    }
}

// ---------------------------------------------------------------------------
// Pass 2: causal flash attention, 2-wave blocks, split-D x2, K in LDS dbuf.
// grid = 4*64*SPLITG = 1280.  g -> xcd=g&7, b=xcd>>1, idx=(g>>3)*2+(xcd&1),
// p=idx&63 (antithetic pair), sblk=idx>>6.  Both waves: same q chunk, same
// kv tiles [nt*sblk/SPLITG, nt*(sblk+1)/SPLITG), nt=c+1, KVB=32.
// Wave w = d-half.  Layouts (mfma_f32_32x32x16_bf16):
//   A: lane l -> row=l&31, k=(l>>5)*8+j ;  B: col=l&31, k=(l>>5)*8+j
//   C: col=l&31, row=(r&3)+8*(r>>2)+4*(l>>5)
// QK^T: S[kv][q] = mfma(A=K rows from LDS, B=Q cols from regs).
// PV:   O^T[d][q] = mfma(A=Vt rows (V loads issued BEFORE K-stage so the
//       compiler's counted vmcnt leaves the K-stage in flight), B=P^T).
// ---------------------------------------------------------------------------
__global__ __launch_bounds__(128, 2) void attn_kernel(
    const bf16_t* __restrict__ Qb, const bf16_t* __restrict__ Kb,
    const bf16_t* __restrict__ Vt,
    float* __restrict__ O0, bf16_t* __restrict__ O1, float* __restrict__ ML)
{
    __shared__ __attribute__((aligned(16))) char smem[2 * 16384];  // K dbuf

    const int g = blockIdx.x;
    const int xcd = g & 7;
    const int b = xcd >> 1;
    const int idx = ((g >> 3) << 1) | (xcd & 1);   // [0, 64*SPLITG)
    const int p = idx & 63;
    const int sblk = idx >> 6;                     // [0, SPLITG)

    const int tid = threadIdx.x;
    const int dhalf = tid >> 6;                    // wave = d-half
    const int l = tid & 63;
    const int q5 = l & 31;
    const int hi = l >> 5;
    const int dbase = dhalf * 128;

    char* cur = smem;
    char* nxt = smem + 16384;

    const int segc[2] = { p, 127 - p };

    auto stageK = [&](int t, char* dst) {
        const size_t rbase = (size_t)(b * SEQ) + (size_t)t * 32;
#pragma unroll
        for (int i = 0; i < 8; ++i) {
            int chunk = i * 128 + tid;        // [0,1024) 16B chunks
            int row = chunk >> 5;             // [0,32)
            int bc  = (chunk & 31) << 4;      // [0,512) step 16
            int scol = bc ^ ((row & 15) << 4);
            GLOAD_LDS16(Kb + (rbase + row) * DM + (scol >> 1), dst + chunk * 16);
        }
    };

    for (int sg = 0; sg < 2; ++sg) {
        const int c = segc[sg];
        const int qbase = c * 32;
        const int nt = c + 1;
        const int T0 = (nt * sblk) / SPLITG;
        const int T1 = (nt * (sblk + 1)) / SPLITG;
        const int qg = qbase + q5;

        __syncthreads();   // prior segment's LDS reads complete (both waves)

        // ---- Q fragments: 64 regs (this lane's q row, both k-halves) ----
        const bf16_t* qrow = Qb + (size_t)(b * SEQ + qg) * DM + hi * 8;
        bf16x8 qf[16];
#pragma unroll
        for (int ks = 0; ks < 16; ++ks)
            qf[ks] = *(const bf16x8*)(qrow + ks * 16);

        f32x16 o[4] = {};
        float m_ = -1e30f, ssum = 0.0f;

        if (T0 < T1) stageK(T0, cur);

        for (int t = T0; t < T1; ++t) {
            const int kv0 = t * 32;
            __syncthreads();   // implicit vmcnt(0): K(t) resident in cur

            // ---- V(t) FIRST: oldest outstanding VMEM -> counted wait later
            const bf16_t* vbase = Vt + ((size_t)b << 20) + kv0 + hi * 8;
            bf16x8 vreg[8];
#pragma unroll
            for (int db = 0; db < 4; ++db) {
                const bf16_t* vr = vbase + (size_t)(dbase + db * 32 + q5) * SEQ;
                vreg[2 * db]     = *(const bf16x8*)(vr);
                vreg[2 * db + 1] = *(const bf16x8*)(vr + 16);
            }
            __builtin_amdgcn_sched_barrier(0);  // pin V-issue before K-stage

            // ---- then stage K(t+1): newest VMEM, stays in flight over PV ----
            if (t + 1 < T1) stageK(t + 1, nxt);

            // ---- S^T = K Q^T : S[kv][q], two acc chains, K from LDS ----
            f32x16 sA = {}, sB = {};
            __builtin_amdgcn_s_setprio(1);
#pragma unroll
            for (int ks = 0; ks < 16; ++ks) {
                bf16x8 kf = *(bf16x8*)(cur + q5 * 512 +
                                       ((ks * 32 + hi * 16) ^ ((q5 & 15) << 4)));
                if (ks & 1) sB = MFMA32(kf, qf[ks], sB);
                else        sA = MFMA32(kf, qf[ks], sA);
            }
            __builtin_amdgcn_s_setprio(0);
            f32x16 sv = sA + sB;

            // ---- causal mask (diagonal tile only) ----
            if (t == c) {
#pragma unroll
                for (int r = 0; r < 16; ++r) {
                    int kv = kv0 + (r & 3) + 8 * (r >> 2) + 4 * hi;
                    if (kv > qg) sv[r] = -1e30f;
                }
            }

            // ---- online softmax, lane-local + one shfl ----
            float rm = sv[0];
#pragma unroll
            for (int r = 1; r < 16; ++r) rm = fmaxf(rm, sv[r]);
            rm = fmaxf(rm, __shfl_xor(rm, 32));
            float mn = (rm > m_ + DEFER_THR) ? rm : m_;
            float al = exp2f(m_ - mn);
            m_ = mn;
            float rs = 0.0f;
#pragma unroll
            for (int r = 0; r < 16; ++r) { sv[r] = exp2f(sv[r] - mn); rs += sv[r]; }
            rs += __shfl_xor(rs, 32);
            ssum = ssum * al + rs;
            if (al != 1.0f) {
#pragma unroll
                for (int db = 0; db < 4; ++db) o[db] *= al;
            }

            // ---- P^T -> bf16 B-fragments (pack + shfl32 + select) ----
            u32 cpk[8], spk[8];
#pragma unroll
            for (int j = 0; j < 8; ++j) cpk[j] = packbf(sv[2 * j], sv[2 * j + 1]);
#pragma unroll
            for (int j = 0; j < 8; ++j) spk[j] = (u32)__shfl_xor((int)cpk[j], 32);
            u32x4 f0, f1;
            f0[0] = hi ? spk[2] : cpk[0];
            f0[1] = hi ? spk[3] : cpk[1];
            f0[2] = hi ? cpk[2] : spk[0];
            f0[3] = hi ? cpk[3] : spk[1];
            f1[0] = hi ? spk[6] : cpk[4];
            f1[1] = hi ? spk[7] : cpk[5];
            f1[2] = hi ? cpk[6] : spk[4];
            f1[3] = hi ? cpk[7] : spk[5];
            bf16x8 pb0 = u4_to_b8(f0);
            bf16x8 pb1 = u4_to_b8(f1);

            // ---- O^T += Vt P^T  (this wave's 128-d half) ----
            __builtin_amdgcn_s_setprio(1);
#pragma unroll
            for (int db = 0; db < 4; ++db) {
                o[db] = MFMA32(vreg[2 * db],     pb0, o[db]);
                o[db] = MFMA32(vreg[2 * db + 1], pb1, o[db]);
            }
            __builtin_amdgcn_s_setprio(0);

            char* tmp = cur; cur = nxt; nxt = tmp;
        }

        // ---- write global partial (this d-half) + (m, l) ----
        const size_t row = (size_t)(b * SEQ + qg);
        if (sblk == 0) {
#pragma unroll
            for (int db = 0; db < 4; ++db)
#pragma unroll
                for (int rr = 0; rr < 4; ++rr) {
                    int d = dbase + db * 32 + rr * 8 + hi * 4;
                    f32x4 v4 = { o[db][rr * 4 + 0], o[db][rr * 4 + 1],
                                 o[db][rr * 4 + 2], o[db][rr * 4 + 3] };
                    *(f32x4*)(O0 + row * DM + d) = v4;
                }
        } else {
            bf16_t* O1s = O1 + (size_t)(sblk - 1) * NELEM;
#pragma unroll
            for (int db = 0; db < 4; ++db)
#pragma unroll
                for (int rr = 0; rr < 4; ++rr) {
                    int d = dbase + db * 32 + rr * 8 + hi * 4;
                    bf16x4 v4;
                    v4[0] = (bf16_t)o[db][rr * 4 + 0];
                    v4[1] = (bf16_t)o[db][rr * 4 + 1];
                    v4[2] = (bf16_t)o[db][rr * 4 + 2];
                    v4[3] = (bf16_t)o[db][rr * 4 + 3];
                    *(bf16x4*)(O1s + row * DM + d) = v4;
                }
        }
        if (dhalf == 0 && hi == 0) {
            ML[(row * SPLITG + sblk) * 2 + 0] = m_;
            ML[(row * SPLITG + sblk) * 2 + 1] = ssum;
        }
    }
}

// ---------------------------------------------------------------------------
// Pass 3: combine split partials.  out = sum_s w_s O_s / sum_s w_s l_s
// ---------------------------------------------------------------------------
__global__ __launch_bounds__(256) void combine_kernel(
    const float* __restrict__ O0, const bf16_t* __restrict__ O1,
    const float* __restrict__ ML, float* __restrict__ out, int split)
{
    const int row = blockIdx.x * 4 + (threadIdx.x >> 6);
    const int l = threadIdx.x & 63;
    const float* mlr = ML + (size_t)row * split * 2;

    float M = -1e30f;
    for (int s = 0; s < split; ++s) M = fmaxf(M, mlr[s * 2]);
    float denom = 0.0f;
    for (int s = 0; s < split; ++s) denom += exp2f(mlr[s * 2] - M) * mlr[s * 2 + 1];
    const float inv = 1.0f / denom;

    const float w0 = exp2f(mlr[0] - M);
    f32x4 a = *(const f32x4*)(O0 + (size_t)row * DM + l * 4);
    f32x4 acc;
#pragma unroll
    for (int j = 0; j < 4; ++j) acc[j] = w0 * a[j];
    for (int s = 1; s < split; ++s) {
        float wss = exp2f(mlr[s * 2] - M);
        bf16x4 bv = *(const bf16x4*)(O1 + (size_t)(s - 1) * NELEM +
                                     (size_t)row * DM + l * 4);
#pragma unroll
        for (int j = 0; j < 4; ++j) acc[j] += wss * (float)bv[j];
    }
    f32x4 r;
#pragma unroll
    for (int j = 0; j < 4; ++j) r[j] = acc[j] * inv;
    *(f32x4*)(out + (size_t)row * DM + l * 4) = r;
}

// ---------------------------------------------------------------------------
extern "C" void kernel_launch(void* const* d_in, const int* in_sizes, int n_in,
                              void* d_out, int out_size, void* d_ws, size_t ws_size,
                              hipStream_t stream) {
    const float* k_in = (const float*)d_in[0];
    const float* q_in = (const float*)d_in[1];
    const float* v_in = (const float*)d_in[2];
    const float* Wk   = (const float*)d_in[3];
    const float* Wq   = (const float*)d_in[4];
    const float* Wv   = (const float*)d_in[5];
    // d_in[6] = causal mask (tril) -- implemented analytically.

    bf16_t* Qb = (bf16_t*)d_ws;
    bf16_t* Kb = Qb + NELEM;
    bf16_t* Vt = Kb + NELEM;
    bf16_t* O1 = Vt + NELEM;                       // (SPLITG-1) bf16 partials
    float*  ML = (float*)(O1 + (size_t)(SPLITG - 1) * NELEM);
    float* outp = (float*)d_out;                   // doubles as slot-0 partial

    proj_kernel<<<dim3(NROWS / 128, DM / 128, 3), 256, 0, stream>>>(
        q_in, k_in, v_in, Wq, Wk, Wv, Qb, Kb, Vt);
    attn_kernel<<<4 * 64 * SPLITG, 128, 0, stream>>>(Qb, Kb, Vt, outp, O1, ML);
    combine_kernel<<<NROWS / 4, 256, 0, stream>>>(outp, O1, ML, outp, SPLITG);
}

// Round 11
// 159.808 us; speedup vs baseline: 2.4901x; 1.1091x over previous
//
#include <hip/hip_runtime.h>

// ---------------------------------------------------------------------------
// SingleHeadAttention: out = softmax(mask((q Wq^T)(k Wk^T)^T / 16)) (v Wv^T)
// B=4, S=4096, D=256, fp32 in/out, bf16 MFMA compute.
// Pass 1: projection GEMM -> ws (Q scaled by log2e/16; V transposed)
// Pass 2: causal flash attention (round-7 structure, verified; single change:
//         V loads issued BEFORE stageK(t+1) so V is the oldest VMEM and the
//         compiler's counted vmcnt before PV leaves the K-stage in flight):
//         128-thr blocks (2 waves), both waves own the SAME 32 q-rows and
//         SAME kv slice; wave = 128-d half.  K tile [32][256] LDS dbuf via
//         global_load_lds; Q in 64 regs; in-register softmax + P repack.
//         Antithetic chunk pair + 4-way kv-split; XCD-aware batch map.
// Pass 3: combine the 4 kv-partials (m/l rescale) -> d_out.
// ---------------------------------------------------------------------------

typedef __bf16 bf16_t;
typedef bf16_t bf16x8 __attribute__((ext_vector_type(8)));
typedef bf16_t bf16x4 __attribute__((ext_vector_type(4)));
typedef float  f32x4  __attribute__((ext_vector_type(4)));
typedef float  f32x16 __attribute__((ext_vector_type(16)));
typedef unsigned int u32;
typedef u32 u32x4 __attribute__((ext_vector_type(4)));

#define MFMA16(a, b, c) __builtin_amdgcn_mfma_f32_16x16x32_bf16((a), (b), (c), 0, 0, 0)
#define MFMA32(a, b, c) __builtin_amdgcn_mfma_f32_32x32x16_bf16((a), (b), (c), 0, 0, 0)

#define GLOAD_LDS16(gsrc, ldst) \
    __builtin_amdgcn_global_load_lds( \
        (const __attribute__((address_space(1))) void*)(gsrc), \
        (__attribute__((address_space(3))) void*)(ldst), 16, 0, 0)

#define NB      4
#define SEQ     4096
#define DM      256
#define NROWS   (NB * SEQ)            // 16384
#define NELEM   ((size_t)NROWS * DM)  // 4194304
#define QSCALE  0.09016844005556021f  // (1/16) * log2(e)
#define DEFER_THR 8.0f                // defer-max threshold (log2 domain)
#define SPLITG  4                     // kv-split (partial slots)

// XOR swizzle for 512B-row tiles (16B granularity) -- proj kernel
__device__ __forceinline__ int swz(int row, int bytecol) {
    return bytecol ^ ((row & 7) << 4);
}

__device__ __forceinline__ u32 packbf(float a, float b) {
    union { bf16_t h; unsigned short s; } ca, cb;
    ca.h = (bf16_t)a; cb.h = (bf16_t)b;
    return (u32)ca.s | ((u32)cb.s << 16);
}

__device__ __forceinline__ bf16x8 u4_to_b8(u32x4 u) {
    union { u32x4 u; bf16x8 b; } cv; cv.u = u; return cv.b;
}

// ---------------------------------------------------------------------------
// Pass 1: projection GEMM.  out[m][n] = sum_k in[m][k] * W[n][k]
// ---------------------------------------------------------------------------
__global__ __launch_bounds__(256) void proj_kernel(
    const float* __restrict__ qin, const float* __restrict__ kin,
    const float* __restrict__ vin,
    const float* __restrict__ Wq, const float* __restrict__ Wk,
    const float* __restrict__ Wv,
    bf16_t* __restrict__ Qb, bf16_t* __restrict__ Kb, bf16_t* __restrict__ Vt)
{
    __shared__ char a_lds[128 * 64 * 2];
    __shared__ char w_lds[128 * 64 * 2];

    const int z = blockIdx.z;
    const float* in = (z == 0) ? qin : (z == 1) ? kin : vin;
    const float* W  = (z == 0) ? Wq  : (z == 1) ? Wk  : Wv;

    const int m0 = blockIdx.x * 128;
    const int n0 = blockIdx.y * 128;
    const int tid = threadIdx.x;
    const int l  = tid & 63;
    const int w  = tid >> 6;
    const int wr = w >> 1, wc = w & 1;
    const int lg = l >> 4, cl = l & 15;

    f32x4 acc[4][4] = {};

    for (int k0 = 0; k0 < DM; k0 += 64) {
#pragma unroll
        for (int i = 0; i < 8; ++i) {
            int chunk = tid + i * 256;
            int row = chunk >> 4;
            int kk  = (chunk & 15) * 4;
            float4 av = *(const float4*)(in + (size_t)(m0 + row) * DM + k0 + kk);
            bf16x4 ap;
            ap[0] = (bf16_t)av.x; ap[1] = (bf16_t)av.y;
            ap[2] = (bf16_t)av.z; ap[3] = (bf16_t)av.w;
            *(bf16x4*)(a_lds + row * 128 + swz(row, kk * 2)) = ap;

            float4 wv4 = *(const float4*)(W + (size_t)(n0 + row) * DM + k0 + kk);
            bf16x4 wp;
            wp[0] = (bf16_t)wv4.x; wp[1] = (bf16_t)wv4.y;
            wp[2] = (bf16_t)wv4.z; wp[3] = (bf16_t)wv4.w;
            *(bf16x4*)(w_lds + row * 128 + swz(row, kk * 2)) = wp;
        }
        __syncthreads();

#pragma unroll
        for (int ks = 0; ks < 2; ++ks) {
            bf16x8 af[4], bfr[4];
#pragma unroll
            for (int mi = 0; mi < 4; ++mi) {
                int row = wr * 64 + mi * 16 + cl;
                int kb2 = (ks * 32 + lg * 8) * 2;
                af[mi] = *(bf16x8*)(a_lds + row * 128 + swz(row, kb2));
            }
#pragma unroll
            for (int ni = 0; ni < 4; ++ni) {
                int row = wc * 64 + ni * 16 + cl;
                int kb2 = (ks * 32 + lg * 8) * 2;
                bfr[ni] = *(bf16x8*)(w_lds + row * 128 + swz(row, kb2));
            }
#pragma unroll
            for (int mi = 0; mi < 4; ++mi)
#pragma unroll
                for (int ni = 0; ni < 4; ++ni)
                    acc[mi][ni] = MFMA16(af[mi], bfr[ni], acc[mi][ni]);
        }
        __syncthreads();
    }

#pragma unroll
    for (int mi = 0; mi < 4; ++mi) {
#pragma unroll
        for (int ni = 0; ni < 4; ++ni) {
            int mbase = m0 + wr * 64 + mi * 16 + lg * 4;
            int ncol  = n0 + wc * 64 + ni * 16 + cl;
            if (z == 0) {
#pragma unroll
                for (int i = 0; i < 4; ++i)
                    Qb[(size_t)(mbase + i) * DM + ncol] = (bf16_t)(acc[mi][ni][i] * QSCALE);
            } else if (z == 1) {
#pragma unroll
                for (int i = 0; i < 4; ++i)
                    Kb[(size_t)(mbase + i) * DM + ncol] = (bf16_t)acc[mi][ni][i];
            } else {
                int bb = mbase >> 12;
                int s0 = mbase & 4095;
                bf16x4 pk;
                pk[0] = (bf16_t)acc[mi][ni][0]; pk[1] = (bf16_t)acc[mi][ni][1];
                pk[2] = (bf16_t)acc[mi][ni][2]; pk[3] = (bf16_t)acc[mi][ni][3];
                *(bf16x4*)(Vt + ((size_t)bb << 20) + (size_t)ncol * SEQ + s0) = pk;
            }
        }
    }
}

// ---------------------------------------------------------------------------
// Pass 2: causal flash attention, 2-wave blocks, split-D x2, K in LDS dbuf.
// grid = 4*64*SPLITG = 1024.  g -> xcd=g&7, b=xcd>>1, idx=(g>>3)*2+(xcd&1),
// p=idx&63 (antithetic pair), sblk=idx>>6.  Both waves: same q chunk, same
// kv tiles [nt*sblk/SPLITG, nt*(sblk+1)/SPLITG), nt=c+1, KVB=32.
// Wave w = d-half.  Layouts (mfma_f32_32x32x16_bf16):
//   A: lane l -> row=l&31, k=(l>>5)*8+j ;  B: col=l&31, k=(l>>5)*8+j
//   C: col=l&31, row=(r&3)+8*(r>>2)+4*(l>>5)
// QK^T: S[kv][q] = mfma(A=K rows from LDS, B=Q cols from regs).
// PV:   O^T[d][q] = mfma(A=Vt rows (loaded first -> oldest VMEM), B=P^T).
// ---------------------------------------------------------------------------
__global__ __launch_bounds__(128, 2) void attn_kernel(
    const bf16_t* __restrict__ Qb, const bf16_t* __restrict__ Kb,
    const bf16_t* __restrict__ Vt,
    float* __restrict__ O0, bf16_t* __restrict__ O1, float* __restrict__ ML)
{
    __shared__ __attribute__((aligned(16))) char smem[2 * 16384];  // K dbuf

    const int g = blockIdx.x;
    const int xcd = g & 7;
    const int b = xcd >> 1;
    const int idx = ((g >> 3) << 1) | (xcd & 1);   // [0, 64*SPLITG)
    const int p = idx & 63;
    const int sblk = idx >> 6;                     // [0, SPLITG)

    const int tid = threadIdx.x;
    const int dhalf = tid >> 6;                    // wave = d-half
    const int l = tid & 63;
    const int q5 = l & 31;
    const int hi = l >> 5;
    const int dbase = dhalf * 128;

    char* cur = smem;
    char* nxt = smem + 16384;

    const int segc[2] = { p, 127 - p };

    auto stageK = [&](int t, char* dst) {
        const size_t rbase = (size_t)(b * SEQ) + (size_t)t * 32;
#pragma unroll
        for (int i = 0; i < 8; ++i) {
            int chunk = i * 128 + tid;        // [0,1024) 16B chunks
            int row = chunk >> 5;             // [0,32)
            int bc  = (chunk & 31) << 4;      // [0,512) step 16
            int scol = bc ^ ((row & 15) << 4);
            GLOAD_LDS16(Kb + (rbase + row) * DM + (scol >> 1), dst + chunk * 16);
        }
    };

    for (int sg = 0; sg < 2; ++sg) {
        const int c = segc[sg];
        const int qbase = c * 32;
        const int nt = c + 1;
        const int T0 = (nt * sblk) / SPLITG;
        const int T1 = (nt * (sblk + 1)) / SPLITG;
        const int qg = qbase + q5;

        __syncthreads();   // prior segment's LDS reads complete (both waves)

        // ---- Q fragments: 64 regs (this lane's q row, both k-halves) ----
        const bf16_t* qrow = Qb + (size_t)(b * SEQ + qg) * DM + hi * 8;
        bf16x8 qf[16];
#pragma unroll
        for (int ks = 0; ks < 16; ++ks)
            qf[ks] = *(const bf16x8*)(qrow + ks * 16);

        f32x16 o[4] = {};
        float m_ = -1e30f, ssum = 0.0f;

        if (T0 < T1) stageK(T0, cur);

        for (int t = T0; t < T1; ++t) {
            const int kv0 = t * 32;
            __syncthreads();   // implicit vmcnt(0): K(t) resident in cur

            // ---- V(t) FIRST: oldest outstanding VMEM, so the compiler's
            //      counted wait before PV leaves the K-stage in flight ----
            const bf16_t* vbase = Vt + ((size_t)b << 20) + kv0 + hi * 8;
            bf16x8 vreg[8];
#pragma unroll
            for (int db = 0; db < 4; ++db) {
                const bf16_t* vr = vbase + (size_t)(dbase + db * 32 + q5) * SEQ;
                vreg[2 * db]     = *(const bf16x8*)(vr);
                vreg[2 * db + 1] = *(const bf16x8*)(vr + 16);
            }

            // ---- then stage K(t+1): newest VMEM, drains at next barrier ----
            if (t + 1 < T1) stageK(t + 1, nxt);

            // ---- S^T = K Q^T : S[kv][q], two acc chains, K from LDS ----
            f32x16 sA = {}, sB = {};
#pragma unroll
            for (int ks = 0; ks < 16; ++ks) {
                bf16x8 kf = *(bf16x8*)(cur + q5 * 512 +
                                       ((ks * 32 + hi * 16) ^ ((q5 & 15) << 4)));
                if (ks & 1) sB = MFMA32(kf, qf[ks], sB);
                else        sA = MFMA32(kf, qf[ks], sA);
            }
            f32x16 sv = sA + sB;

            // ---- causal mask (diagonal tile only) ----
            if (t == c) {
#pragma unroll
                for (int r = 0; r < 16; ++r) {
                    int kv = kv0 + (r & 3) + 8 * (r >> 2) + 4 * hi;
                    if (kv > qg) sv[r] = -1e30f;
                }
            }

            // ---- online softmax, lane-local + one shfl ----
            float rm = sv[0];
#pragma unroll
            for (int r = 1; r < 16; ++r) rm = fmaxf(rm, sv[r]);
            rm = fmaxf(rm, __shfl_xor(rm, 32));
            float mn = (rm > m_ + DEFER_THR) ? rm : m_;
            float al = exp2f(m_ - mn);
            m_ = mn;
            float rs = 0.0f;
#pragma unroll
            for (int r = 0; r < 16; ++r) { sv[r] = exp2f(sv[r] - mn); rs += sv[r]; }
            rs += __shfl_xor(rs, 32);
            ssum = ssum * al + rs;
            if (al != 1.0f) {
#pragma unroll
                for (int db = 0; db < 4; ++db) o[db] *= al;
            }

            // ---- P^T -> bf16 B-fragments (pack + shfl32 + select) ----
            u32 cpk[8], spk[8];
#pragma unroll
            for (int j = 0; j < 8; ++j) cpk[j] = packbf(sv[2 * j], sv[2 * j + 1]);
#pragma unroll
            for (int j = 0; j < 8; ++j) spk[j] = (u32)__shfl_xor((int)cpk[j], 32);
            u32x4 f0, f1;
            f0[0] = hi ? spk[2] : cpk[0];
            f0[1] = hi ? spk[3] : cpk[1];
            f0[2] = hi ? cpk[2] : spk[0];
            f0[3] = hi ? cpk[3] : spk[1];
            f1[0] = hi ? spk[6] : cpk[4];
            f1[1] = hi ? spk[7] : cpk[5];
            f1[2] = hi ? cpk[6] : spk[4];
            f1[3] = hi ? cpk[7] : spk[5];
            bf16x8 pb0 = u4_to_b8(f0);
            bf16x8 pb1 = u4_to_b8(f1);

            // ---- O^T += Vt P^T  (this wave's 128-d half) ----
#pragma unroll
            for (int db = 0; db < 4; ++db) {
                o[db] = MFMA32(vreg[2 * db],     pb0, o[db]);
                o[db] = MFMA32(vreg[2 * db + 1], pb1, o[db]);
            }

            char* tmp = cur; cur = nxt; nxt = tmp;
        }

        // ---- write global partial (this d-half) + (m, l) ----
        const size_t row = (size_t)(b * SEQ + qg);
        if (sblk == 0) {
#pragma unroll
            for (int db = 0; db < 4; ++db)
#pragma unroll
                for (int rr = 0; rr < 4; ++rr) {
                    int d = dbase + db * 32 + rr * 8 + hi * 4;
                    f32x4 v4 = { o[db][rr * 4 + 0], o[db][rr * 4 + 1],
                                 o[db][rr * 4 + 2], o[db][rr * 4 + 3] };
                    *(f32x4*)(O0 + row * DM + d) = v4;
                }
        } else {
            bf16_t* O1s = O1 + (size_t)(sblk - 1) * NELEM;
#pragma unroll
            for (int db = 0; db < 4; ++db)
#pragma unroll
                for (int rr = 0; rr < 4; ++rr) {
                    int d = dbase + db * 32 + rr * 8 + hi * 4;
                    bf16x4 v4;
                    v4[0] = (bf16_t)o[db][rr * 4 + 0];
                    v4[1] = (bf16_t)o[db][rr * 4 + 1];
                    v4[2] = (bf16_t)o[db][rr * 4 + 2];
                    v4[3] = (bf16_t)o[db][rr * 4 + 3];
                    *(bf16x4*)(O1s + row * DM + d) = v4;
                }
        }
        if (dhalf == 0 && hi == 0) {
            ML[(row * SPLITG + sblk) * 2 + 0] = m_;
            ML[(row * SPLITG + sblk) * 2 + 1] = ssum;
        }
    }
}

// ---------------------------------------------------------------------------
// Pass 3: combine split partials.  out = sum_s w_s O_s / sum_s w_s l_s
// ---------------------------------------------------------------------------
__global__ __launch_bounds__(256) void combine_kernel(
    const float* __restrict__ O0, const bf16_t* __restrict__ O1,
    const float* __restrict__ ML, float* __restrict__ out, int split)
{
    const int row = blockIdx.x * 4 + (threadIdx.x >> 6);
    const int l = threadIdx.x & 63;
    const float* mlr = ML + (size_t)row * split * 2;

    float M = -1e30f;
    for (int s = 0; s < split; ++s) M = fmaxf(M, mlr[s * 2]);
    float denom = 0.0f;
    for (int s = 0; s < split; ++s) denom += exp2f(mlr[s * 2] - M) * mlr[s * 2 + 1];
    const float inv = 1.0f / denom;

    const float w0 = exp2f(mlr[0] - M);
    f32x4 a = *(const f32x4*)(O0 + (size_t)row * DM + l * 4);
    f32x4 acc;
#pragma unroll
    for (int j = 0; j < 4; ++j) acc[j] = w0 * a[j];
    for (int s = 1; s < split; ++s) {
        float wss = exp2f(mlr[s * 2] - M);
        bf16x4 bv = *(const bf16x4*)(O1 + (size_t)(s - 1) * NELEM +
                                     (size_t)row * DM + l * 4);
#pragma unroll
        for (int j = 0; j < 4; ++j) acc[j] += wss * (float)bv[j];
    }
    f32x4 r;
#pragma unroll
    for (int j = 0; j < 4; ++j) r[j] = acc[j] * inv;
    *(f32x4*)(out + (size_t)row * DM + l * 4) = r;
}

// ---------------------------------------------------------------------------
extern "C" void kernel_launch(void* const* d_in, const int* in_sizes, int n_in,
                              void* d_out, int out_size, void* d_ws, size_t ws_size,
                              hipStream_t stream) {
    const float* k_in = (const float*)d_in[0];
    const float* q_in = (const float*)d_in[1];
    const float* v_in = (const float*)d_in[2];
    const float* Wk   = (const float*)d_in[3];
    const float* Wq   = (const float*)d_in[4];
    const float* Wv   = (const float*)d_in[5];
    // d_in[6] = causal mask (tril) -- implemented analytically.

    bf16_t* Qb = (bf16_t*)d_ws;
    bf16_t* Kb = Qb + NELEM;
    bf16_t* Vt = Kb + NELEM;
    bf16_t* O1 = Vt + NELEM;                       // (SPLITG-1) bf16 partials
    float*  ML = (float*)(O1 + (size_t)(SPLITG - 1) * NELEM);
    float* outp = (float*)d_out;                   // doubles as slot-0 partial

    proj_kernel<<<dim3(NROWS / 128, DM / 128, 3), 256, 0, stream>>>(
        q_in, k_in, v_in, Wq, Wk, Wv, Qb, Kb, Vt);
    attn_kernel<<<4 * 64 * SPLITG, 128, 0, stream>>>(Qb, Kb, Vt, outp, O1, ML);
    combine_kernel<<<NROWS / 4, 256, 0, stream>>>(outp, O1, ML, outp, SPLITG);
}

// Round 12
// 138.514 us; speedup vs baseline: 2.8730x; 1.1537x over previous
//
#include <hip/hip_runtime.h>

// ---------------------------------------------------------------------------
// SingleHeadAttention: out = softmax(mask((q Wq^T)(k Wk^T)^T / 16)) (v Wv^T)
// B=4, S=4096, D=256, fp32 in/out, bf16 MFMA compute.
// Pass 1: projection GEMM -> ws (Q scaled by log2e/16; V transposed)
// Pass 2: causal flash attention (round-7 structure, verified best; single
//         change vs R7: XCD index encodes (batch, kv-half) so each XCD's L2
//         working set is ~8MB instead of 16MB):
//         128-thr blocks (2 waves), both waves own the SAME 32 q-rows and
//         SAME kv slice; wave = 128-d half.  K tile [32][256] LDS dbuf via
//         global_load_lds; Q in 64 regs; V reg-prefetch at tile top (after
//         K-stage -- R7 order, R11 showed V-first regresses).  In-register
//         softmax + P repack.  Antithetic chunk pair + 4-way kv-split.
// Pass 3: combine the 4 kv-partials (m/l rescale) -> d_out.
// ---------------------------------------------------------------------------

typedef __bf16 bf16_t;
typedef bf16_t bf16x8 __attribute__((ext_vector_type(8)));
typedef bf16_t bf16x4 __attribute__((ext_vector_type(4)));
typedef float  f32x4  __attribute__((ext_vector_type(4)));
typedef float  f32x16 __attribute__((ext_vector_type(16)));
typedef unsigned int u32;
typedef u32 u32x4 __attribute__((ext_vector_type(4)));

#define MFMA16(a, b, c) __builtin_amdgcn_mfma_f32_16x16x32_bf16((a), (b), (c), 0, 0, 0)
#define MFMA32(a, b, c) __builtin_amdgcn_mfma_f32_32x32x16_bf16((a), (b), (c), 0, 0, 0)

#define GLOAD_LDS16(gsrc, ldst) \
    __builtin_amdgcn_global_load_lds( \
        (const __attribute__((address_space(1))) void*)(gsrc), \
        (__attribute__((address_space(3))) void*)(ldst), 16, 0, 0)

#define NB      4
#define SEQ     4096
#define DM      256
#define NROWS   (NB * SEQ)            // 16384
#define NELEM   ((size_t)NROWS * DM)  // 4194304
#define QSCALE  0.09016844005556021f  // (1/16) * log2(e)
#define DEFER_THR 8.0f                // defer-max threshold (log2 domain)
#define SPLITG  4                     // kv-split (partial slots)

// XOR swizzle for 512B-row tiles (16B granularity) -- proj kernel
__device__ __forceinline__ int swz(int row, int bytecol) {
    return bytecol ^ ((row & 7) << 4);
}

__device__ __forceinline__ u32 packbf(float a, float b) {
    union { bf16_t h; unsigned short s; } ca, cb;
    ca.h = (bf16_t)a; cb.h = (bf16_t)b;
    return (u32)ca.s | ((u32)cb.s << 16);
}

__device__ __forceinline__ bf16x8 u4_to_b8(u32x4 u) {
    union { u32x4 u; bf16x8 b; } cv; cv.u = u; return cv.b;
}

// ---------------------------------------------------------------------------
// Pass 1: projection GEMM.  out[m][n] = sum_k in[m][k] * W[n][k]
// ---------------------------------------------------------------------------
__global__ __launch_bounds__(256) void proj_kernel(
    const float* __restrict__ qin, const float* __restrict__ kin,
    const float* __restrict__ vin,
    const float* __restrict__ Wq, const float* __restrict__ Wk,
    const float* __restrict__ Wv,
    bf16_t* __restrict__ Qb, bf16_t* __restrict__ Kb, bf16_t* __restrict__ Vt)
{
    __shared__ char a_lds[128 * 64 * 2];
    __shared__ char w_lds[128 * 64 * 2];

    const int z = blockIdx.z;
    const float* in = (z == 0) ? qin : (z == 1) ? kin : vin;
    const float* W  = (z == 0) ? Wq  : (z == 1) ? Wk  : Wv;

    const int m0 = blockIdx.x * 128;
    const int n0 = blockIdx.y * 128;
    const int tid = threadIdx.x;
    const int l  = tid & 63;
    const int w  = tid >> 6;
    const int wr = w >> 1, wc = w & 1;
    const int lg = l >> 4, cl = l & 15;

    f32x4 acc[4][4] = {};

    for (int k0 = 0; k0 < DM; k0 += 64) {
#pragma unroll
        for (int i = 0; i < 8; ++i) {
            int chunk = tid + i * 256;
            int row = chunk >> 4;
            int kk  = (chunk & 15) * 4;
            float4 av = *(const float4*)(in + (size_t)(m0 + row) * DM + k0 + kk);
            bf16x4 ap;
            ap[0] = (bf16_t)av.x; ap[1] = (bf16_t)av.y;
            ap[2] = (bf16_t)av.z; ap[3] = (bf16_t)av.w;
            *(bf16x4*)(a_lds + row * 128 + swz(row, kk * 2)) = ap;

            float4 wv4 = *(const float4*)(W + (size_t)(n0 + row) * DM + k0 + kk);
            bf16x4 wp;
            wp[0] = (bf16_t)wv4.x; wp[1] = (bf16_t)wv4.y;
            wp[2] = (bf16_t)wv4.z; wp[3] = (bf16_t)wv4.w;
            *(bf16x4*)(w_lds + row * 128 + swz(row, kk * 2)) = wp;
        }
        __syncthreads();

#pragma unroll
        for (int ks = 0; ks < 2; ++ks) {
            bf16x8 af[4], bfr[4];
#pragma unroll
            for (int mi = 0; mi < 4; ++mi) {
                int row = wr * 64 + mi * 16 + cl;
                int kb2 = (ks * 32 + lg * 8) * 2;
                af[mi] = *(bf16x8*)(a_lds + row * 128 + swz(row, kb2));
            }
#pragma unroll
            for (int ni = 0; ni < 4; ++ni) {
                int row = wc * 64 + ni * 16 + cl;
                int kb2 = (ks * 32 + lg * 8) * 2;
                bfr[ni] = *(bf16x8*)(w_lds + row * 128 + swz(row, kb2));
            }
#pragma unroll
            for (int mi = 0; mi < 4; ++mi)
#pragma unroll
                for (int ni = 0; ni < 4; ++ni)
                    acc[mi][ni] = MFMA16(af[mi], bfr[ni], acc[mi][ni]);
        }
        __syncthreads();
    }

#pragma unroll
    for (int mi = 0; mi < 4; ++mi) {
#pragma unroll
        for (int ni = 0; ni < 4; ++ni) {
            int mbase = m0 + wr * 64 + mi * 16 + lg * 4;
            int ncol  = n0 + wc * 64 + ni * 16 + cl;
            if (z == 0) {
#pragma unroll
                for (int i = 0; i < 4; ++i)
                    Qb[(size_t)(mbase + i) * DM + ncol] = (bf16_t)(acc[mi][ni][i] * QSCALE);
            } else if (z == 1) {
#pragma unroll
                for (int i = 0; i < 4; ++i)
                    Kb[(size_t)(mbase + i) * DM + ncol] = (bf16_t)acc[mi][ni][i];
            } else {
                int bb = mbase >> 12;
                int s0 = mbase & 4095;
                bf16x4 pk;
                pk[0] = (bf16_t)acc[mi][ni][0]; pk[1] = (bf16_t)acc[mi][ni][1];
                pk[2] = (bf16_t)acc[mi][ni][2]; pk[3] = (bf16_t)acc[mi][ni][3];
                *(bf16x4*)(Vt + ((size_t)bb << 20) + (size_t)ncol * SEQ + s0) = pk;
            }
        }
    }
}

// ---------------------------------------------------------------------------
// Pass 2: causal flash attention, 2-wave blocks, split-D x2, K in LDS dbuf.
// grid = 4*64*SPLITG = 1024.  XCD-aware map: xcd = g&7 encodes (batch,
// kv-half): b = xcd>>1, shi = xcd&1; r = g>>3; p = r&63 (antithetic pair),
// sblk = shi*2 + (r>>6).  Per-XCD kv working set ~8MB (vs 16MB batch-only).
// Both waves: same q chunk, same kv tiles [nt*sblk/4, nt*(sblk+1)/4), nt=c+1,
// KVB=32.  Wave w = d-half.  Layouts (mfma_f32_32x32x16_bf16):
//   A: lane l -> row=l&31, k=(l>>5)*8+j ;  B: col=l&31, k=(l>>5)*8+j
//   C: col=l&31, row=(r&3)+8*(r>>2)+4*(l>>5)
// QK^T: S[kv][q] = mfma(A=K rows from LDS, B=Q cols from regs).
// PV:   O^T[d][q] = mfma(A=Vt rows (reg-prefetched), B=P^T cols).
// ---------------------------------------------------------------------------
__global__ __launch_bounds__(128, 2) void attn_kernel(
    const bf16_t* __restrict__ Qb, const bf16_t* __restrict__ Kb,
    const bf16_t* __restrict__ Vt,
    float* __restrict__ O0, bf16_t* __restrict__ O1, float* __restrict__ ML)
{
    __shared__ __attribute__((aligned(16))) char smem[2 * 16384];  // K dbuf

    const int g = blockIdx.x;
    const int xcd = g & 7;
    const int b = xcd >> 1;                        // batch -> 2 XCDs
    const int shi = xcd & 1;                       // kv-half -> XCD
    const int r = g >> 3;                          // [0,128)
    const int p = r & 63;                          // antithetic pair index
    const int sblk = shi * 2 + (r >> 6);           // [0, SPLITG)

    const int tid = threadIdx.x;
    const int dhalf = tid >> 6;                    // wave = d-half
    const int l = tid & 63;
    const int q5 = l & 31;
    const int hi = l >> 5;
    const int dbase = dhalf * 128;

    char* cur = smem;
    char* nxt = smem + 16384;

    const int segc[2] = { p, 127 - p };

    auto stageK = [&](int t, char* dst) {
        const size_t rbase = (size_t)(b * SEQ) + (size_t)t * 32;
#pragma unroll
        for (int i = 0; i < 8; ++i) {
            int chunk = i * 128 + tid;        // [0,1024) 16B chunks
            int row = chunk >> 5;             // [0,32)
            int bc  = (chunk & 31) << 4;      // [0,512) step 16
            int scol = bc ^ ((row & 15) << 4);
            GLOAD_LDS16(Kb + (rbase + row) * DM + (scol >> 1), dst + chunk * 16);
        }
    };

    for (int sg = 0; sg < 2; ++sg) {
        const int c = segc[sg];
        const int qbase = c * 32;
        const int nt = c + 1;
        const int T0 = (nt * sblk) / SPLITG;
        const int T1 = (nt * (sblk + 1)) / SPLITG;
        const int qg = qbase + q5;

        __syncthreads();   // prior segment's LDS reads complete (both waves)

        // ---- Q fragments: 64 regs (this lane's q row, both k-halves) ----
        const bf16_t* qrow = Qb + (size_t)(b * SEQ + qg) * DM + hi * 8;
        bf16x8 qf[16];
#pragma unroll
        for (int ks = 0; ks < 16; ++ks)
            qf[ks] = *(const bf16x8*)(qrow + ks * 16);

        f32x16 o[4] = {};
        float m_ = -1e30f, ssum = 0.0f;

        if (T0 < T1) stageK(T0, cur);

        for (int t = T0; t < T1; ++t) {
            const int kv0 = t * 32;
            __syncthreads();   // implicit vmcnt(0): K(t) resident in cur

            // ---- stage K(t+1) (R7 order: K first, then V) ----
            if (t + 1 < T1) stageK(t + 1, nxt);

            // ---- V prefetch: this wave's 128-d half, 8 x 16B ----
            const bf16_t* vbase = Vt + ((size_t)b << 20) + kv0 + hi * 8;
            bf16x8 vreg[8];
#pragma unroll
            for (int db = 0; db < 4; ++db) {
                const bf16_t* vr = vbase + (size_t)(dbase + db * 32 + q5) * SEQ;
                vreg[2 * db]     = *(const bf16x8*)(vr);
                vreg[2 * db + 1] = *(const bf16x8*)(vr + 16);
            }

            // ---- S^T = K Q^T : S[kv][q], two acc chains, K from LDS ----
            f32x16 sA = {}, sB = {};
#pragma unroll
            for (int ks = 0; ks < 16; ++ks) {
                bf16x8 kf = *(bf16x8*)(cur + q5 * 512 +
                                       ((ks * 32 + hi * 16) ^ ((q5 & 15) << 4)));
                if (ks & 1) sB = MFMA32(kf, qf[ks], sB);
                else        sA = MFMA32(kf, qf[ks], sA);
            }
            f32x16 sv = sA + sB;

            // ---- causal mask (diagonal tile only) ----
            if (t == c) {
#pragma unroll
                for (int rr2 = 0; rr2 < 16; ++rr2) {
                    int kv = kv0 + (rr2 & 3) + 8 * (rr2 >> 2) + 4 * hi;
                    if (kv > qg) sv[rr2] = -1e30f;
                }
            }

            // ---- online softmax, lane-local + one shfl ----
            float rm = sv[0];
#pragma unroll
            for (int rr2 = 1; rr2 < 16; ++rr2) rm = fmaxf(rm, sv[rr2]);
            rm = fmaxf(rm, __shfl_xor(rm, 32));
            float mn = (rm > m_ + DEFER_THR) ? rm : m_;
            float al = exp2f(m_ - mn);
            m_ = mn;
            float rs = 0.0f;
#pragma unroll
            for (int rr2 = 0; rr2 < 16; ++rr2) { sv[rr2] = exp2f(sv[rr2] - mn); rs += sv[rr2]; }
            rs += __shfl_xor(rs, 32);
            ssum = ssum * al + rs;
            if (al != 1.0f) {
#pragma unroll
                for (int db = 0; db < 4; ++db) o[db] *= al;
            }

            // ---- P^T -> bf16 B-fragments (pack + shfl32 + select) ----
            u32 cpk[8], spk[8];
#pragma unroll
            for (int j = 0; j < 8; ++j) cpk[j] = packbf(sv[2 * j], sv[2 * j + 1]);
#pragma unroll
            for (int j = 0; j < 8; ++j) spk[j] = (u32)__shfl_xor((int)cpk[j], 32);
            u32x4 f0, f1;
            f0[0] = hi ? spk[2] : cpk[0];
            f0[1] = hi ? spk[3] : cpk[1];
            f0[2] = hi ? cpk[2] : spk[0];
            f0[3] = hi ? cpk[3] : spk[1];
            f1[0] = hi ? spk[6] : cpk[4];
            f1[1] = hi ? spk[7] : cpk[5];
            f1[2] = hi ? cpk[6] : spk[4];
            f1[3] = hi ? cpk[7] : spk[5];
            bf16x8 pb0 = u4_to_b8(f0);
            bf16x8 pb1 = u4_to_b8(f1);

            // ---- O^T += Vt P^T  (this wave's 128-d half) ----
#pragma unroll
            for (int db = 0; db < 4; ++db) {
                o[db] = MFMA32(vreg[2 * db],     pb0, o[db]);
                o[db] = MFMA32(vreg[2 * db + 1], pb1, o[db]);
            }

            char* tmp = cur; cur = nxt; nxt = tmp;
        }

        // ---- write global partial (this d-half) + (m, l) ----
        const size_t row = (size_t)(b * SEQ + qg);
        if (sblk == 0) {
#pragma unroll
            for (int db = 0; db < 4; ++db)
#pragma unroll
                for (int rr = 0; rr < 4; ++rr) {
                    int d = dbase + db * 32 + rr * 8 + hi * 4;
                    f32x4 v4 = { o[db][rr * 4 + 0], o[db][rr * 4 + 1],
                                 o[db][rr * 4 + 2], o[db][rr * 4 + 3] };
                    *(f32x4*)(O0 + row * DM + d) = v4;
                }
        } else {
            bf16_t* O1s = O1 + (size_t)(sblk - 1) * NELEM;
#pragma unroll
            for (int db = 0; db < 4; ++db)
#pragma unroll
                for (int rr = 0; rr < 4; ++rr) {
                    int d = dbase + db * 32 + rr * 8 + hi * 4;
                    bf16x4 v4;
                    v4[0] = (bf16_t)o[db][rr * 4 + 0];
                    v4[1] = (bf16_t)o[db][rr * 4 + 1];
                    v4[2] = (bf16_t)o[db][rr * 4 + 2];
                    v4[3] = (bf16_t)o[db][rr * 4 + 3];
                    *(bf16x4*)(O1s + row * DM + d) = v4;
                }
        }
        if (dhalf == 0 && hi == 0) {
            ML[(row * SPLITG + sblk) * 2 + 0] = m_;
            ML[(row * SPLITG + sblk) * 2 + 1] = ssum;
        }
    }
}

// ---------------------------------------------------------------------------
// Pass 3: combine split partials.  out = sum_s w_s O_s / sum_s w_s l_s
// ---------------------------------------------------------------------------
__global__ __launch_bounds__(256) void combine_kernel(
    const float* __restrict__ O0, const bf16_t* __restrict__ O1,
    const float* __restrict__ ML, float* __restrict__ out, int split)
{
    const int row = blockIdx.x * 4 + (threadIdx.x >> 6);
    const int l = threadIdx.x & 63;
    const float* mlr = ML + (size_t)row * split * 2;

    float M = -1e30f;
    for (int s = 0; s < split; ++s) M = fmaxf(M, mlr[s * 2]);
    float denom = 0.0f;
    for (int s = 0; s < split; ++s) denom += exp2f(mlr[s * 2] - M) * mlr[s * 2 + 1];
    const float inv = 1.0f / denom;

    const float w0 = exp2f(mlr[0] - M);
    f32x4 a = *(const f32x4*)(O0 + (size_t)row * DM + l * 4);
    f32x4 acc;
#pragma unroll
    for (int j = 0; j < 4; ++j) acc[j] = w0 * a[j];
    for (int s = 1; s < split; ++s) {
        float wss = exp2f(mlr[s * 2] - M);
        bf16x4 bv = *(const bf16x4*)(O1 + (size_t)(s - 1) * NELEM +
                                     (size_t)row * DM + l * 4);
#pragma unroll
        for (int j = 0; j < 4; ++j) acc[j] += wss * (float)bv[j];
    }
    f32x4 r;
#pragma unroll
    for (int j = 0; j < 4; ++j) r[j] = acc[j] * inv;
    *(f32x4*)(out + (size_t)row * DM + l * 4) = r;
}

// ---------------------------------------------------------------------------
extern "C" void kernel_launch(void* const* d_in, const int* in_sizes, int n_in,
                              void* d_out, int out_size, void* d_ws, size_t ws_size,
                              hipStream_t stream) {
    const float* k_in = (const float*)d_in[0];
    const float* q_in = (const float*)d_in[1];
    const float* v_in = (const float*)d_in[2];
    const float* Wk   = (const float*)d_in[3];
    const float* Wq   = (const float*)d_in[4];
    const float* Wv   = (const float*)d_in[5];
    // d_in[6] = causal mask (tril) -- implemented analytically.

    bf16_t* Qb = (bf16_t*)d_ws;
    bf16_t* Kb = Qb + NELEM;
    bf16_t* Vt = Kb + NELEM;
    bf16_t* O1 = Vt + NELEM;                       // (SPLITG-1) bf16 partials
    float*  ML = (float*)(O1 + (size_t)(SPLITG - 1) * NELEM);
    float* outp = (float*)d_out;                   // doubles as slot-0 partial

    proj_kernel<<<dim3(NROWS / 128, DM / 128, 3), 256, 0, stream>>>(
        q_in, k_in, v_in, Wq, Wk, Wv, Qb, Kb, Vt);
    attn_kernel<<<4 * 64 * SPLITG, 128, 0, stream>>>(Qb, Kb, Vt, outp, O1, ML);
    combine_kernel<<<NROWS / 4, 256, 0, stream>>>(outp, O1, ML, outp, SPLITG);
}